// Round 1
// baseline (125.603 us; speedup 1.0000x reference)
//
#include <hip/hip_runtime.h>
#include <hip/hip_bf16.h>
#include <stdint.h>

#define NBATCH 16
#define NT 2048
#define NC 64
#define QT 128
#define KT 128
#define SC_LOG2E 11.5415603f  // 8 * log2(e)

typedef __bf16 bf16x8 __attribute__((ext_vector_type(8)));
typedef float f32x4 __attribute__((ext_vector_type(4)));

extern "C" __device__ float __ocml_exp2_f32(float);

static __device__ __forceinline__ unsigned short f2bf(float f) {
  union { float f; uint32_t u; } a; a.f = f;
  uint32_t u = a.u;
  uint32_t r = (u + 0x7FFFu + ((u >> 16) & 1u)) >> 16;
  return (unsigned short)r;
}
static __device__ __forceinline__ float bf2f(unsigned short h) {
  union { uint32_t u; float f; } a; a.u = ((uint32_t)h) << 16;
  return a.f;
}

// ---------------------------------------------------------------------------
// Kernel 1: q,k,v projections. 64 rows per block.
// Outputs: khi/klo/qhi/qlo as [B*T][64] bf16 (hi/lo split), vt as [B][64][T] bf16.
// ---------------------------------------------------------------------------
__global__ __launch_bounds__(256, 2) void proj_kernel(
    const float* __restrict__ x,
    const float* __restrict__ Wk, const float* __restrict__ bk,
    const float* __restrict__ Wq, const float* __restrict__ bq,
    const float* __restrict__ Wv, const float* __restrict__ bv,
    unsigned short* __restrict__ khi, unsigned short* __restrict__ klo,
    unsigned short* __restrict__ qhi, unsigned short* __restrict__ qlo,
    unsigned short* __restrict__ vt)
{
  __shared__ __align__(16) char smem[65536];
  const int XH = 0, XL = 8192, WTH = 16384, WTL = 40960, VTB = 0; // VTB aliases XH
  const int tid = (int)threadIdx.x;
  const int l = tid & 63, w = tid >> 6;
  const int lr = l & 15, lg = l >> 4;
  const int blk = (int)blockIdx.x;
  const int rowbase = blk * 64;
  const int bb = blk >> 5;          // 32 blocks per batch

  // stage x tile (64x64 f32) as hi/lo bf16, swizzled
  for (int c = tid; c < 1024; c += 256) {
    int row = c >> 4, d0 = (c & 15) * 4;
    const float4 xv = *(const float4*)(x + (size_t)(rowbase + row) * NC + d0);
    unsigned short h0 = f2bf(xv.x), h1 = f2bf(xv.y), h2 = f2bf(xv.z), h3 = f2bf(xv.w);
    unsigned short m0 = f2bf(xv.x - bf2f(h0)), m1 = f2bf(xv.y - bf2f(h1));
    unsigned short m2 = f2bf(xv.z - bf2f(h2)), m3 = f2bf(xv.w - bf2f(h3));
    uint2 ph, pl;
    ph.x = (uint32_t)h0 | ((uint32_t)h1 << 16); ph.y = (uint32_t)h2 | ((uint32_t)h3 << 16);
    pl.x = (uint32_t)m0 | ((uint32_t)m1 << 16); pl.y = (uint32_t)m2 | ((uint32_t)m3 << 16);
    int byteoff = (row * 128 + d0 * 2) ^ ((row & 7) << 4);
    *(uint2*)(smem + XH + byteoff) = ph;
    *(uint2*)(smem + XL + byteoff) = pl;
  }
  // stage W^T (192 og-rows x 64 c-cols) as hi/lo bf16, swizzled
  for (int cw = tid; cw < 3072; cw += 256) {
    int og = cw >> 4, c0 = (cw & 15) * 4;
    const float* Wm = (og < 64) ? Wk : (og < 128 ? Wq : Wv);
    int o = og & 63;
    float w0 = Wm[(size_t)(c0 + 0) * 64 + o];
    float w1 = Wm[(size_t)(c0 + 1) * 64 + o];
    float w2 = Wm[(size_t)(c0 + 2) * 64 + o];
    float w3 = Wm[(size_t)(c0 + 3) * 64 + o];
    unsigned short h0 = f2bf(w0), h1 = f2bf(w1), h2 = f2bf(w2), h3 = f2bf(w3);
    unsigned short m0 = f2bf(w0 - bf2f(h0)), m1 = f2bf(w1 - bf2f(h1));
    unsigned short m2 = f2bf(w2 - bf2f(h2)), m3 = f2bf(w3 - bf2f(h3));
    uint2 ph, pl;
    ph.x = (uint32_t)h0 | ((uint32_t)h1 << 16); ph.y = (uint32_t)h2 | ((uint32_t)h3 << 16);
    pl.x = (uint32_t)m0 | ((uint32_t)m1 << 16); pl.y = (uint32_t)m2 | ((uint32_t)m3 << 16);
    int byteoff = (og * 128 + c0 * 2) ^ ((og & 7) << 4);
    *(uint2*)(smem + WTH + byteoff) = ph;
    *(uint2*)(smem + WTL + byteoff) = pl;
  }
  __syncthreads();

  // A-frags for this wave's 16 rows
  bf16x8 Ah[2], Al[2];
  {
    int row = w * 16 + lr;
#pragma unroll
    for (int dc = 0; dc < 2; ++dc) {
      int byteoff = (row * 128 + (dc * 32 + lg * 8) * 2) ^ ((row & 7) << 4);
      Ah[dc] = *(const bf16x8*)(smem + XH + byteoff);
      Al[dc] = *(const bf16x8*)(smem + XL + byteoff);
    }
  }
  f32x4 acc[12];
#pragma unroll
  for (int nb = 0; nb < 12; ++nb) {
    f32x4 a = {0.f, 0.f, 0.f, 0.f};
    int og = nb * 16 + lr;
#pragma unroll
    for (int dc = 0; dc < 2; ++dc) {
      int byteoff = (og * 128 + (dc * 32 + lg * 8) * 2) ^ ((og & 7) << 4);
      bf16x8 bh = *(const bf16x8*)(smem + WTH + byteoff);
      bf16x8 bl = *(const bf16x8*)(smem + WTL + byteoff);
      a = __builtin_amdgcn_mfma_f32_16x16x32_bf16(Ah[dc], bh, a, 0, 0, 0);
      a = __builtin_amdgcn_mfma_f32_16x16x32_bf16(Al[dc], bh, a, 0, 0, 0);
      a = __builtin_amdgcn_mfma_f32_16x16x32_bf16(Ah[dc], bl, a, 0, 0, 0);
    }
    acc[nb] = a;
  }
  __syncthreads();  // done reading XH/XL; VTB may now alias

  // epilogue: bias add, hi/lo split out for k/q, v into LDS transpose buffer
#pragma unroll
  for (int nb = 0; nb < 12; ++nb) {
    int og = nb * 16 + lr;
    const float* bp = (og < 64) ? bk : (og < 128 ? bq : bv);
    float bias = bp[og & 63];
#pragma unroll
    for (int r = 0; r < 4; ++r) {
      float val = acc[nb][r] + bias;
      int tloc = w * 16 + lg * 4 + r;
      size_t gt = (size_t)(rowbase + tloc);
      if (og < 64) {
        unsigned short h = f2bf(val);
        khi[gt * 64 + og] = h;
        klo[gt * 64 + og] = f2bf(val - bf2f(h));
      } else if (og < 128) {
        unsigned short h = f2bf(val);
        qhi[gt * 64 + (og - 64)] = h;
        qlo[gt * 64 + (og - 64)] = f2bf(val - bf2f(h));
      } else {
        int o = og - 128;
        int byteoff = (o * 128 + tloc * 2) ^ ((o & 7) << 4);
        *(unsigned short*)(smem + VTB + byteoff) = f2bf(val);
      }
    }
  }
  __syncthreads();
  // copy v^T tile [64 o][64 t] to global [B][64][T]
  for (int cc = tid; cc < 512; cc += 256) {
    int o = cc >> 3, t0 = (cc & 7) * 8;
    int byteoff = (o * 128 + t0 * 2) ^ ((o & 7) << 4);
    uint4 v = *(const uint4*)(smem + VTB + byteoff);
    *(uint4*)(vt + ((size_t)bb * 64 + o) * NT + (size_t)(blk & 31) * 64 + t0) = v;
  }
}

// ---------------------------------------------------------------------------
// Kernel 2: flash attention. 1 block per (batch, 128-row Q tile), 4 waves.
// S^T = K·Q^T (3-term hi/lo) -> online softmax (stats at col=lane&15) ->
// P via wave-private swizzled LDS -> O += P·V (V^T staged).
// ---------------------------------------------------------------------------
__global__ __launch_bounds__(256, 2) void attn_kernel(
    const unsigned short* __restrict__ khi, const unsigned short* __restrict__ klo,
    const unsigned short* __restrict__ qhi, const unsigned short* __restrict__ qlo,
    const unsigned short* __restrict__ vt,
    float* __restrict__ out)
{
  __shared__ __align__(16) char smem[49152];
  const int KHI = 0, KLO = 16384, VTB = 32768; // P (4x8KB) aliases KHI+KLO
  const int tid = (int)threadIdx.x;
  const int l = tid & 63, w = tid >> 6;
  const int lr = l & 15, lg = l >> 4;
  // XCD-aware swizzle: 256 blocks, 8 XCDs -> each XCD gets 2 whole batches
  const int lb = ((int)(blockIdx.x & 7) << 5) | ((int)blockIdx.x >> 3);
  const int bb = lb >> 4;
  const int qt = lb & 15;

  // --- Q prologue: stage into KHI/KLO, hoist frags to registers
  {
    const unsigned short* srcH = qhi + ((size_t)bb * NT + (size_t)qt * QT) * 64;
    const unsigned short* srcL = qlo + ((size_t)bb * NT + (size_t)qt * QT) * 64;
    for (int c = tid; c < 1024; c += 256) {
      int row = c >> 3;
      int byteoff = (c * 16) ^ ((row & 7) << 4);
      *(uint4*)(smem + KHI + byteoff) = *(const uint4*)((const char*)srcH + c * 16);
      *(uint4*)(smem + KLO + byteoff) = *(const uint4*)((const char*)srcL + c * 16);
    }
  }
  __syncthreads();
  bf16x8 Qh[2][2], Ql[2][2];
#pragma unroll
  for (int qb = 0; qb < 2; ++qb) {
    int row = w * 32 + qb * 16 + lr;
#pragma unroll
    for (int dc = 0; dc < 2; ++dc) {
      int byteoff = (row * 128 + (dc * 32 + lg * 8) * 2) ^ ((row & 7) << 4);
      Qh[qb][dc] = *(const bf16x8*)(smem + KHI + byteoff);
      Ql[qb][dc] = *(const bf16x8*)(smem + KLO + byteoff);
    }
  }

  f32x4 O[2][4];
#pragma unroll
  for (int qb = 0; qb < 2; ++qb)
#pragma unroll
    for (int nb = 0; nb < 4; ++nb) O[qb][nb] = {0.f, 0.f, 0.f, 0.f};
  float mrun[2] = {-1e30f, -1e30f};
  float lrun[2] = {0.f, 0.f};

  for (int it = 0; it < NT / KT; ++it) {
    __syncthreads();  // previous iter's LDS reads (and Q-frag reads) complete
    // stage K hi/lo tiles [128][64] and V^T tile [64][128]
    {
      const unsigned short* sKh = khi + ((size_t)bb * NT + (size_t)it * KT) * 64;
      const unsigned short* sKl = klo + ((size_t)bb * NT + (size_t)it * KT) * 64;
      for (int c = tid; c < 1024; c += 256) {
        int row = c >> 3;
        int byteoff = (c * 16) ^ ((row & 7) << 4);
        *(uint4*)(smem + KHI + byteoff) = *(const uint4*)((const char*)sKh + c * 16);
        *(uint4*)(smem + KLO + byteoff) = *(const uint4*)((const char*)sKl + c * 16);
      }
      const unsigned short* sV = vt + (size_t)bb * 64 * NT + (size_t)it * KT;
      for (int c = tid; c < 1024; c += 256) {
        int o = c >> 4, k0 = (c & 15) * 8;
        int byteoff = (c * 16) ^ ((o & 7) << 4);
        *(uint4*)(smem + VTB + byteoff) = *(const uint4*)(sV + (size_t)o * NT + k0);
      }
    }
    __syncthreads();
    // S^T[key][qrow] = K · Q^T, 3-term hi/lo split
    f32x4 S[8][2];
#pragma unroll
    for (int kb = 0; kb < 8; ++kb) {
      int krow = kb * 16 + lr;
      bf16x8 Ah[2], Al[2];
#pragma unroll
      for (int dc = 0; dc < 2; ++dc) {
        int byteoff = (krow * 128 + (dc * 32 + lg * 8) * 2) ^ ((krow & 7) << 4);
        Ah[dc] = *(const bf16x8*)(smem + KHI + byteoff);
        Al[dc] = *(const bf16x8*)(smem + KLO + byteoff);
      }
#pragma unroll
      for (int qb = 0; qb < 2; ++qb) {
        f32x4 a = {0.f, 0.f, 0.f, 0.f};
#pragma unroll
        for (int dc = 0; dc < 2; ++dc) {
          a = __builtin_amdgcn_mfma_f32_16x16x32_bf16(Ah[dc], Qh[qb][dc], a, 0, 0, 0);
          a = __builtin_amdgcn_mfma_f32_16x16x32_bf16(Al[dc], Qh[qb][dc], a, 0, 0, 0);
          a = __builtin_amdgcn_mfma_f32_16x16x32_bf16(Ah[dc], Ql[qb][dc], a, 0, 0, 0);
        }
        S[kb][qb] = a;
      }
    }
    __syncthreads();  // all waves done with KHI/KLO; P may alias them now
    // online softmax; stats live at lanes keyed by (l&15)=qrow
#pragma unroll
    for (int qb = 0; qb < 2; ++qb) {
      float mt = -1e30f;
#pragma unroll
      for (int kb = 0; kb < 8; ++kb)
#pragma unroll
        for (int r = 0; r < 4; ++r) mt = fmaxf(mt, S[kb][qb][r]);
      mt = fmaxf(mt, __shfl_xor(mt, 16));
      mt = fmaxf(mt, __shfl_xor(mt, 32));
      float mnew = fmaxf(mrun[qb], mt);
      float alpha = __ocml_exp2_f32((mrun[qb] - mnew) * SC_LOG2E);
      mrun[qb] = mnew;
      float ts = 0.f;
      int prow = qb * 16 + lr;
#pragma unroll
      for (int kb = 0; kb < 8; ++kb) {
        float p0 = __ocml_exp2_f32((S[kb][qb][0] - mnew) * SC_LOG2E);
        float p1 = __ocml_exp2_f32((S[kb][qb][1] - mnew) * SC_LOG2E);
        float p2 = __ocml_exp2_f32((S[kb][qb][2] - mnew) * SC_LOG2E);
        float p3 = __ocml_exp2_f32((S[kb][qb][3] - mnew) * SC_LOG2E);
        ts += (p0 + p1) + (p2 + p3);
        uint2 pk;
        pk.x = (uint32_t)f2bf(p0) | ((uint32_t)f2bf(p1) << 16);
        pk.y = (uint32_t)f2bf(p2) | ((uint32_t)f2bf(p3) << 16);
        int byteoff = (prow * 256 + kb * 32 + lg * 8) ^ ((prow & 7) << 4);
        *(uint2*)(smem + w * 8192 + byteoff) = pk;
      }
      ts += __shfl_xor(ts, 16);
      ts += __shfl_xor(ts, 32);
      lrun[qb] = lrun[qb] * alpha + ts;
      // rescale O (O rows are lg*4+r; alpha lives at lane&15=row)
      float ar[4];
#pragma unroll
      for (int r = 0; r < 4; ++r) ar[r] = __shfl(alpha, (l & 48) + lg * 4 + r);
#pragma unroll
      for (int nb = 0; nb < 4; ++nb)
#pragma unroll
        for (int r = 0; r < 4; ++r) O[qb][nb][r] *= ar[r];
    }
    __builtin_amdgcn_s_waitcnt(0);  // wave-private P writes complete before reads
    asm volatile("" ::: "memory");
    // O += P · V   (A = P [qrow][key], B = V via V^T [d][key])
#pragma unroll
    for (int kc = 0; kc < 4; ++kc) {
      bf16x8 Ap[2];
#pragma unroll
      for (int qb = 0; qb < 2; ++qb) {
        int prow = qb * 16 + lr;
        int byteoff = (prow * 256 + kc * 64 + lg * 16) ^ ((prow & 7) << 4);
        Ap[qb] = *(const bf16x8*)(smem + w * 8192 + byteoff);
      }
      bf16x8 Bv[4];
#pragma unroll
      for (int nb = 0; nb < 4; ++nb) {
        int drow = nb * 16 + lr;
        int byteoff = (drow * 256 + kc * 64 + lg * 16) ^ ((drow & 7) << 4);
        Bv[nb] = *(const bf16x8*)(smem + VTB + byteoff);
      }
#pragma unroll
      for (int qb = 0; qb < 2; ++qb)
#pragma unroll
        for (int nb = 0; nb < 4; ++nb)
          O[qb][nb] = __builtin_amdgcn_mfma_f32_16x16x32_bf16(Ap[qb], Bv[nb], O[qb][nb], 0, 0, 0);
    }
  }
  // epilogue: O / l, write f32
#pragma unroll
  for (int qb = 0; qb < 2; ++qb) {
    float inv = 1.0f / lrun[qb];
    float ir[4];
#pragma unroll
    for (int r = 0; r < 4; ++r) ir[r] = __shfl(inv, (l & 48) + lg * 4 + r);
#pragma unroll
    for (int nb = 0; nb < 4; ++nb) {
      int d = nb * 16 + lr;
#pragma unroll
      for (int r = 0; r < 4; ++r) {
        int t = qt * QT + w * 32 + qb * 16 + lg * 4 + r;
        out[((size_t)bb * NT + t) * 64 + d] = O[qb][nb][r] * ir[r];
      }
    }
  }
}

extern "C" void kernel_launch(void* const* d_in, const int* in_sizes, int n_in,
                              void* d_out, int out_size, void* d_ws, size_t ws_size,
                              hipStream_t stream) {
  const float* x  = (const float*)d_in[0];
  const float* Wk = (const float*)d_in[1];
  const float* bk = (const float*)d_in[2];
  const float* Wq = (const float*)d_in[3];
  const float* bq = (const float*)d_in[4];
  const float* Wv = (const float*)d_in[5];
  const float* bv = (const float*)d_in[6];
  float* out = (float*)d_out;

  const size_t NE = (size_t)NBATCH * NT * 64;
  unsigned short* ws = (unsigned short*)d_ws;
  unsigned short* khi = ws;
  unsigned short* klo = ws + NE;
  unsigned short* qhi = ws + 2 * NE;
  unsigned short* qlo = ws + 3 * NE;
  unsigned short* vt  = ws + 4 * NE;

  proj_kernel<<<dim3((NBATCH * NT) / 64), dim3(256), 0, stream>>>(
      x, Wk, bk, Wq, bq, Wv, bv, khi, klo, qhi, qlo, vt);
  attn_kernel<<<dim3(NBATCH * (NT / QT)), dim3(256), 0, stream>>>(
      khi, klo, qhi, qlo, vt, out);
}